// Round 1
// baseline (972.332 us; speedup 1.0000x reference)
//
#include <hip/hip_runtime.h>

// TBE pooled-sum forward.
// weights: [T, E, D] fp32, indices: [T*B*L] int32 (flat, table-major bags),
// offsets: [T*B+1] int32. Output: [B, T*D] fp32 where out[b, t*D+d] = pooled[t*B+b, d].
//
// One wave per bag. Per bag:
//   - ONE coalesced index load (lane l reads indices[start+l]), indices then
//     distributed in-register via ds_bpermute (__shfl) -> gathers have no
//     memory dependency and issue back-to-back (deep MLP).
//   - TWO rows per vmem instruction: lanes 0-31 load row 2p (float4/lane,
//     512B), lanes 32-63 load row 2p+1. 1KB per global_load_dwordx4.
//     Half-wave partial sums folded with one __shfl_xor(...,32) at the end.
//   - 32-bit byte offsets off an SGPR-resident table base (table id is
//     block-uniform: 1024 blocks per table).

constexpr int T = 16;
constexpr int E = 100000;
constexpr int D = 128;
constexpr int BAGS_PER_TABLE = 4096;
constexpr int NUM_BAGS = T * BAGS_PER_TABLE;     // 65536
constexpr int WAVES_PER_BLOCK = 4;               // block = 256 threads
constexpr int BLOCKS_PER_TABLE = BAGS_PER_TABLE / WAVES_PER_BLOCK;  // 1024
static_assert(BAGS_PER_TABLE % WAVES_PER_BLOCK == 0, "table must be block-aligned");

typedef float f4 __attribute__((ext_vector_type(4)));

__global__ __launch_bounds__(256) void tbe_pool_kernel(
    const float* __restrict__ weights,
    const int* __restrict__ indices,
    const int* __restrict__ offsets,
    float* __restrict__ out)
{
    const int wave = threadIdx.x >> 6;
    const int lane = threadIdx.x & 63;
    const int half = lane >> 5;          // 0: even row of pair, 1: odd row
    const int l32  = lane & 31;          // float4 slot within a 512B row

    // Table id is block-uniform (1024 blocks per table) -> SGPR base address.
    const int t            = blockIdx.x / BLOCKS_PER_TABLE;
    const int bag_in_table = (blockIdx.x % BLOCKS_PER_TABLE) * WAVES_PER_BLOCK + wave;
    const int bag          = t * BAGS_PER_TABLE + bag_in_table;

    const int start = offsets[bag];
    const int end   = offsets[bag + 1];

    const char* __restrict__ tbl =
        reinterpret_cast<const char*>(weights) + (size_t)t * E * D * sizeof(float);
    const unsigned laneByte = (unsigned)(l32 * 16);

    f4 a0 = {0.f, 0.f, 0.f, 0.f};
    f4 a1 = {0.f, 0.f, 0.f, 0.f};
    f4 a2 = {0.f, 0.f, 0.f, 0.f};
    f4 a3 = {0.f, 0.f, 0.f, 0.f};

    for (int base = start; base < end; base += 64) {
        const int navail = min(64, end - base);

        // One coalesced load covers all this chunk's bag indices.
        int myidx = 0;
        if (lane < navail) myidx = indices[base + lane];

        const int npairs = navail >> 1;
        int p = 0;
        for (; p + 4 <= npairs; p += 4) {
            // Row index for this lane's half of each pair (ds_bpermute, no mem dep).
            const int r0 = __shfl(myidx, 2 * (p + 0) + half);
            const int r1 = __shfl(myidx, 2 * (p + 1) + half);
            const int r2 = __shfl(myidx, 2 * (p + 2) + half);
            const int r3 = __shfl(myidx, 2 * (p + 3) + half);
            // 4 independent 1KB loads (2 rows each) in flight.
            const f4 v0 = *reinterpret_cast<const f4*>(tbl + ((unsigned)r0 * 512u + laneByte));
            const f4 v1 = *reinterpret_cast<const f4*>(tbl + ((unsigned)r1 * 512u + laneByte));
            const f4 v2 = *reinterpret_cast<const f4*>(tbl + ((unsigned)r2 * 512u + laneByte));
            const f4 v3 = *reinterpret_cast<const f4*>(tbl + ((unsigned)r3 * 512u + laneByte));
            a0 += v0; a1 += v1; a2 += v2; a3 += v3;
        }
        for (; p < npairs; ++p) {
            const int r0 = __shfl(myidx, 2 * p + half);
            const f4 v0 = *reinterpret_cast<const f4*>(tbl + ((unsigned)r0 * 512u + laneByte));
            a0 += v0;
        }
        if (navail & 1) {
            // Single leftover row: lower half-wave loads its 512B.
            const int r0 = __shfl(myidx, navail - 1);
            if (half == 0) {
                const f4 v0 = *reinterpret_cast<const f4*>(tbl + ((unsigned)r0 * 512u + laneByte));
                a0 += v0;
            }
        }
    }

    f4 acc = (a0 + a1) + (a2 + a3);
    // Fold odd-row partial sums (lanes 32-63) onto lanes 0-31.
    acc.x += __shfl_xor(acc.x, 32);
    acc.y += __shfl_xor(acc.y, 32);
    acc.z += __shfl_xor(acc.z, 32);
    acc.w += __shfl_xor(acc.w, 32);

    if (half == 0) {
        // out[b, t*D + 4*l32 .. +3] — 512B contiguous per wave, coalesced.
        f4* __restrict__ o = reinterpret_cast<f4*>(
            out + (size_t)bag_in_table * (T * D) + (size_t)t * D);
        __builtin_nontemporal_store(acc, o + l32);
    }
}

extern "C" void kernel_launch(void* const* d_in, const int* in_sizes, int n_in,
                              void* d_out, int out_size, void* d_ws, size_t ws_size,
                              hipStream_t stream) {
    const float* weights = (const float*)d_in[0];
    const int*   indices = (const int*)d_in[1];
    const int*   offsets = (const int*)d_in[2];
    float*       out     = (float*)d_out;

    const int grid = NUM_BAGS / WAVES_PER_BLOCK;  // 16384 blocks x 256 threads
    tbe_pool_kernel<<<grid, 256, 0, stream>>>(weights, indices, offsets, out);
}